// Round 6
// baseline (401.664 us; speedup 1.0000x reference)
//
#include <hip/hip_runtime.h>
#include <hip/hip_bf16.h>

#define Bn 8
#define Cn 64
#define Np 16384      // H*W
#define Sc 32         // clusters
#define On 64         // output channels
#define Dd 576        // C*9
#define KM_ITERS 8
#define KMB 64        // kmeans blocks per batch (256 px each)
#define KBLK 32       // centp GEMM blocks per batch (512 px each)

typedef float f32x4 __attribute__((ext_vector_type(4)));
typedef __bf16 bf16x8 __attribute__((ext_vector_type(8)));
typedef __bf16 bf16x4 __attribute__((ext_vector_type(4)));

__device__ __forceinline__ void split3(float v, __bf16& h, __bf16& m, __bf16& lo) {
    h = (__bf16)v;
    float r = v - (float)h;
    m = (__bf16)r;
    lo = (__bf16)(r - (float)m);
}

__device__ __forceinline__ void split2(float v, __bf16& h, __bf16& m) {
    h = (__bf16)v;
    m = (__bf16)(v - (float)h);
}

// ---------------- x[b][c][n] -> fh/fm[b][n][c] (bf16 2-term split) ----------------
__global__ __launch_bounds__(256) void featbf2_k(const float* __restrict__ x,
                                                 __bf16* __restrict__ fh,
                                                 __bf16* __restrict__ fm) {
    __shared__ float tile[64][65];
    int b = blockIdx.y, n0 = blockIdx.x * 64, t = threadIdx.x;
    int j = t & 63, c0 = (t >> 6) * 16;
    #pragma unroll
    for (int cc = 0; cc < 16; ++cc)
        tile[c0 + cc][j] = x[((size_t)b * Cn + c0 + cc) * Np + n0 + j];
    __syncthreads();
    int n_loc = t & 63, cq = (t >> 6) * 16;
    bf16x8 vh[2], vm[2];
    #pragma unroll
    for (int g = 0; g < 2; ++g)
        #pragma unroll
        for (int u = 0; u < 8; ++u) {
            __bf16 h, m;
            split2(tile[cq + g * 8 + u][n_loc], h, m);
            vh[g][u] = h; vm[g][u] = m;
        }
    size_t base = ((size_t)b * Np + n0 + n_loc) * Cn + cq;
    *(bf16x8*)&fh[base] = vh[0]; *(bf16x8*)&fh[base + 8] = vh[1];
    *(bf16x8*)&fm[base] = vm[0]; *(bf16x8*)&fm[base + 8] = vm[1];
}

// ---------------- centroid init (f32 + 2-term bf16 + cnorm) ----------------
__global__ __launch_bounds__(64) void init_cent3_k(const float* __restrict__ x,
                                                   float* __restrict__ cent_f32,
                                                   __bf16* __restrict__ ch_,
                                                   __bf16* __restrict__ cm_,
                                                   float* __restrict__ cnorm) {
    int b = blockIdx.y, s = blockIdx.x, c = threadIdx.x;
    int n = s * (Np / Sc);
    float v = x[((size_t)b * Cn + c) * Np + n];
    int o = (b * Sc + s) * Cn + c;
    cent_f32[o] = v;
    __bf16 h, m; split2(v, h, m);
    ch_[o] = h; cm_[o] = m;
    float sq = v * v;
    #pragma unroll
    for (int off = 32; off >= 1; off >>= 1) sq += __shfl_down(sq, off);
    if (c == 0) cnorm[b * Sc + s] = sq;
}

// ---------------- w2 -> bf16, permuted to [k][o][c] ----------------
__global__ __launch_bounds__(256) void w2prep_k(const float* __restrict__ w2,
                                                __bf16* __restrict__ w2kg) {
    int i = blockIdx.x * 256 + threadIdx.x;   // 36864 total
    int k = i >> 12, rem = i & 4095, o = rem >> 6, c = rem & 63;
    w2kg[i] = (__bf16)w2[o * Dd + c * 9 + k];
}

// ---------------- fused Lloyd iteration: 4-product MFMA assign + exact fallback + MFMA update ----------------
__global__ __launch_bounds__(256, 3) void kmeans_fused3_k(
        const float* __restrict__ x,
        const __bf16* __restrict__ fh, const __bf16* __restrict__ fm,
        const float* __restrict__ cent_f32,
        const __bf16* __restrict__ ch_, const __bf16* __restrict__ cm_,
        const float* __restrict__ cnorm,
        int* __restrict__ idxg, float* __restrict__ gpart,
        float* __restrict__ out_idx, int do_update) {
    __shared__ __bf16 Bt_h[64][72];
    __shared__ __bf16 Bt_m[64][72];
    __shared__ __bf16 Bt_l[64][72];
    __shared__ __bf16 A_oh[32][72];
    __shared__ int idx_s[256];
    __shared__ int redint[4][32];
    __shared__ float centf_s[32][64];
    __shared__ float cnorm_s[32];
    int b = blockIdx.y, n0 = blockIdx.x * 256, t = threadIdx.x;
    int w = t >> 6, l = t & 63, arow = l & 15, kg = l >> 4;

    // stage f32 centroids + norms (for exact fallback)
    for (int i = t; i < Sc * Cn; i += 256) ((float*)centf_s)[i] = cent_f32[b * Sc * Cn + i];
    if (t < Sc) cnorm_s[t] = cnorm[b * Sc + t];

    // ---- phase A: scores via 2-term split MFMA (4 products: hh, hm, mh, mm) ----
    bf16x8 cbh[2][2], cbm[2][2];
    #pragma unroll
    for (int st = 0; st < 2; ++st)
        #pragma unroll
        for (int kt = 0; kt < 2; ++kt) {
            size_t cb = (size_t)(b * Sc + st * 16 + arow) * Cn + kt * 32 + kg * 8;
            cbh[st][kt] = *(const bf16x8*)&ch_[cb];
            cbm[st][kt] = *(const bf16x8*)&cm_[cb];
        }
    float cn0 = cnorm[b * Sc + arow];
    float cn1 = cnorm[b * Sc + 16 + arow];

    f32x4 dacc[4][2];
    #pragma unroll
    for (int mt = 0; mt < 4; ++mt) {
        dacc[mt][0] = (f32x4){0.f, 0.f, 0.f, 0.f};
        dacc[mt][1] = (f32x4){0.f, 0.f, 0.f, 0.f};
    }
    #pragma unroll
    for (int mt = 0; mt < 4; ++mt) {
        size_t fb = ((size_t)b * Np + n0 + w * 64 + mt * 16 + arow) * Cn;
        bf16x8 ah[2], am2[2];
        #pragma unroll
        for (int kt = 0; kt < 2; ++kt) {
            ah[kt]  = *(const bf16x8*)&fh[fb + kt * 32 + kg * 8];
            am2[kt] = *(const bf16x8*)&fm[fb + kt * 32 + kg * 8];
        }
        #pragma unroll
        for (int st = 0; st < 2; ++st)
            #pragma unroll
            for (int kt = 0; kt < 2; ++kt) {
                dacc[mt][st] = __builtin_amdgcn_mfma_f32_16x16x32_bf16(ah[kt],  cbh[st][kt], dacc[mt][st], 0, 0, 0);
                dacc[mt][st] = __builtin_amdgcn_mfma_f32_16x16x32_bf16(ah[kt],  cbm[st][kt], dacc[mt][st], 0, 0, 0);
                dacc[mt][st] = __builtin_amdgcn_mfma_f32_16x16x32_bf16(am2[kt], cbh[st][kt], dacc[mt][st], 0, 0, 0);
                dacc[mt][st] = __builtin_amdgcn_mfma_f32_16x16x32_bf16(am2[kt], cbm[st][kt], dacc[mt][st], 0, 0, 0);
            }
    }
    __syncthreads();   // centf_s staged before fallback may read it

    // argmin + top-2 gap + exact fallback for near-ties
    // error bound of 4-product approx vs f32: ~1.2e-3 worst case; thr=0.02 gives >4x margin
    #pragma unroll
    for (int mt = 0; mt < 4; ++mt)
        #pragma unroll
        for (int r = 0; r < 4; ++r) {
            float dA = cn0 - 2.f * dacc[mt][0][r];
            float dB = cn1 - 2.f * dacc[mt][1][r];
            float d1, d2; int s1;
            if (dB < dA) { d1 = dB; s1 = arow + 16; d2 = dA; }
            else         { d1 = dA; s1 = arow;      d2 = dB; }
            #pragma unroll
            for (int mk = 1; mk < 16; mk <<= 1) {
                float d1o = __shfl_xor(d1, mk);
                int   s1o = __shfl_xor(s1, mk);
                float d2o = __shfl_xor(d2, mk);
                float big = fmaxf(d1, d1o);
                d2 = fminf(fminf(d2, d2o), big);
                if (d1o < d1 || (d1o == d1 && s1o < s1)) { d1 = d1o; s1 = s1o; }
            }
            int pix = w * 64 + mt * 16 + kg * 4 + r;
            bool writer = (arow == 0);
            if (writer) idx_s[pix] = s1;
            bool flag = writer && ((d2 - d1) < 0.02f);
            unsigned long long bal = __ballot(flag);
            while (bal) {
                int src = __ffsll(bal) - 1;
                bal &= bal - 1;
                int fp = w * 64 + mt * 16 + (src >> 4) * 4 + r;
                int n = n0 + fp;
                int s = l & 31, c0 = (l >> 5) * 32;
                float acc2 = 0.f;
                #pragma unroll 8
                for (int c = 0; c < 32; ++c)
                    acc2 = fmaf(x[((size_t)b * Cn + c0 + c) * Np + n], centf_s[s][c0 + c], acc2);
                acc2 += __shfl_xor(acc2, 32);
                float dd = cnorm_s[s] - 2.f * acc2;
                int ss = s;
                #pragma unroll
                for (int mk = 1; mk < 32; mk <<= 1) {
                    float ddo = __shfl_xor(dd, mk);
                    int   sso = __shfl_xor(ss, mk);
                    if (ddo < dd || (ddo == dd && sso < ss)) { dd = ddo; ss = sso; }
                }
                if (l == 0) idx_s[fp] = ss;
            }
        }
    __syncthreads();

    int best = idx_s[t];
    if (out_idx) {   // final pass: write idx outputs
        idxg[b * Np + n0 + t] = best;
        out_idx[b * Np + n0 + t] = (float)best;
    }
    if (!do_update) return;

    // deterministic counts via ballot
    #pragma unroll 4
    for (int s = 0; s < Sc; ++s) {
        unsigned long long bal = __ballot(best == s);
        if (l == 0) redint[w][s] = __popcll(bal);
    }

    // ---- phase B: per-block cluster sums via one-hot MFMA (3-term B, exact-class) ----
    f32x4 uacc[2];
    uacc[0] = (f32x4){0.f, 0.f, 0.f, 0.f};
    uacc[1] = (f32x4){0.f, 0.f, 0.f, 0.f};
    for (int mc = 0; mc < 4; ++mc) {
        __syncthreads();
        {   // stage Bt chunk [c][64 m] 3-term from x (coalesced channel-major)
            int c = t >> 2, mq = t & 3;
            const float* xp = &x[((size_t)b * Cn + c) * Np + n0 + mc * 64 + mq * 16];
            #pragma unroll
            for (int u = 0; u < 4; ++u) {
                f32x4 v = *(const f32x4*)&xp[u * 4];
                bf16x4 hv, mv, lv;
                #pragma unroll
                for (int e = 0; e < 4; ++e) {
                    __bf16 h, m, lo; split3(v[e], h, m, lo);
                    hv[e] = h; mv[e] = m; lv[e] = lo;
                }
                *(bf16x4*)&Bt_h[c][mq * 16 + u * 4] = hv;
                *(bf16x4*)&Bt_m[c][mq * 16 + u * 4] = mv;
                *(bf16x4*)&Bt_l[c][mq * 16 + u * 4] = lv;
            }
        }
        {   // build one-hot A columns
            int m = t & 63, sq = t >> 6;
            int bm = idx_s[mc * 64 + m];
            #pragma unroll
            for (int u = 0; u < 8; ++u)
                A_oh[sq * 8 + u][m] = (sq * 8 + u == bm) ? (__bf16)1.0f : (__bf16)0.0f;
        }
        __syncthreads();
        #pragma unroll
        for (int kh = 0; kh < 2; ++kh) {
            bf16x8 bh = *(const bf16x8*)&Bt_h[w * 16 + arow][kh * 32 + kg * 8];
            bf16x8 bm2 = *(const bf16x8*)&Bt_m[w * 16 + arow][kh * 32 + kg * 8];
            bf16x8 bl2 = *(const bf16x8*)&Bt_l[w * 16 + arow][kh * 32 + kg * 8];
            #pragma unroll
            for (int smt = 0; smt < 2; ++smt) {
                bf16x8 af = *(const bf16x8*)&A_oh[smt * 16 + arow][kh * 32 + kg * 8];
                uacc[smt] = __builtin_amdgcn_mfma_f32_16x16x32_bf16(af, bh,  uacc[smt], 0, 0, 0);
                uacc[smt] = __builtin_amdgcn_mfma_f32_16x16x32_bf16(af, bm2, uacc[smt], 0, 0, 0);
                uacc[smt] = __builtin_amdgcn_mfma_f32_16x16x32_bf16(af, bl2, uacc[smt], 0, 0, 0);
            }
        }
    }
    float* gp = &gpart[(size_t)(b * KMB + blockIdx.x) * (Sc * 65)];
    #pragma unroll
    for (int smt = 0; smt < 2; ++smt)
        #pragma unroll
        for (int r = 0; r < 4; ++r)
            gp[(smt * 16 + kg * 4 + r) * 65 + w * 16 + arow] = uacc[smt][r];
    if (t < Sc)
        gp[t * 65 + 64] = (float)(redint[0][t] + redint[1][t] + redint[2][t] + redint[3][t]);
}

// ---------------- reduce partials -> new centroids (4-wave parallel) ----------------
__global__ __launch_bounds__(256) void update_reduce3_k(const float* __restrict__ gpart,
                                                        float* __restrict__ cent_f32,
                                                        __bf16* __restrict__ ch_,
                                                        __bf16* __restrict__ cm_,
                                                        float* __restrict__ cnorm) {
    __shared__ float psum[4][64];
    __shared__ float pcnt[4];
    int b = blockIdx.y, s = blockIdx.x, t = threadIdx.x;
    int w = t >> 6, c = t & 63;
    float sum = 0.f, cnt = 0.f;
    #pragma unroll 4
    for (int blk = w * 16; blk < w * 16 + 16; ++blk) {
        const float* g = &gpart[(size_t)(b * KMB + blk) * (Sc * 65) + s * 65];
        sum += g[c];
        if (c == 0) cnt += g[64];
    }
    psum[w][c] = sum;
    if (c == 0) pcnt[w] = cnt;
    __syncthreads();
    if (t < 64) {
        float m = psum[0][t] + psum[1][t] + psum[2][t] + psum[3][t];
        float ct = pcnt[0] + pcnt[1] + pcnt[2] + pcnt[3];
        float mean = m / fmaxf(ct, 1.f);
        int o = (b * Sc + s) * Cn + t;
        cent_f32[o] = mean;
        __bf16 h, mm; split2(mean, h, mm);
        ch_[o] = h; cm_[o] = mm;
        float sq = mean * mean;
        #pragma unroll
        for (int off = 32; off >= 1; off >>= 1) sq += __shfl_down(sq, off);
        if (t == 0) cnorm[b * Sc + s] = sq;
    }
}

// ---------------- cluster patch sums via one-hot MFMA GEMM ----------------
__global__ __launch_bounds__(512) void centp_mfma_k(const float* __restrict__ x,
                                                    const int* __restrict__ idxg,
                                                    float* __restrict__ partialP) {
    __shared__ __bf16 Amat[288 * 56];
    __shared__ __bf16 Bt[64 * 56];
    int b = blockIdx.y, kb = blockIdx.x, t = threadIdx.x;
    int w = t >> 6, l = t & 63;
    int wm = w >> 2, wn = w & 3;
    int arow = l & 15, kg = l >> 4;
    f32x4 acc[9];
    #pragma unroll
    for (int j = 0; j < 9; ++j) acc[j] = (f32x4){0.f, 0.f, 0.f, 0.f};

    int m_base = kb * 512;
    for (int kt = 0; kt < 16; ++kt) {
        int m0 = m_base + kt * 32;
        #pragma unroll
        for (int j = 0; j < 9; ++j) {
            int i = t + 512 * j;
            int row = i >> 4, dc = i & 15;
            *(unsigned*)&Amat[row * 56 + dc * 2] = 0u;
        }
        {
            int c = t >> 3, k0 = (t & 7) * 4;
            f32x4 v = *(const f32x4*)&x[((size_t)b * Cn + c) * Np + m0 + k0];
            bf16x4 bv4;
            bv4[0] = (__bf16)v.x; bv4[1] = (__bf16)v.y;
            bv4[2] = (__bf16)v.z; bv4[3] = (__bf16)v.w;
            *(bf16x4*)&Bt[c * 56 + k0] = bv4;
        }
        __syncthreads();
        if (t < 288) {
            int m = t & 31, k = t >> 5;
            int mg = m0 + m, mh = mg >> 7, mw = mg & 127;
            int dh = k / 3 - 1, dw = k % 3 - 1;
            int nh = mh - dh, nw = mw - dw;
            if (((unsigned)nh < 128u) && ((unsigned)nw < 128u)) {
                int s = idxg[b * Np + (nh << 7) + nw];
                Amat[(s * 9 + k) * 56 + m] = (__bf16)1.0f;
            }
        }
        __syncthreads();
        bf16x8 bfrag = *(const bf16x8*)&Bt[(wn * 16 + arow) * 56 + kg * 8];
        #pragma unroll
        for (int j = 0; j < 9; ++j) {
            int mt = wm * 9 + j;
            bf16x8 afrag = *(const bf16x8*)&Amat[(mt * 16 + arow) * 56 + kg * 8];
            acc[j] = __builtin_amdgcn_mfma_f32_16x16x32_bf16(afrag, bfrag, acc[j], 0, 0, 0);
        }
        __syncthreads();
    }
    float* P = partialP + (size_t)(b * KBLK + kb) * 288 * 64;
    #pragma unroll
    for (int j = 0; j < 9; ++j) {
        int R0 = (wm * 9 + j) * 16 + kg * 4;
        int col = wn * 16 + arow;
        #pragma unroll
        for (int r = 0; r < 4; ++r) P[(size_t)(R0 + r) * 64 + col] = acc[j][r];
    }
}

// ---------------- reduce patch partials + counts -> softmax attention ----------------
__global__ __launch_bounds__(576) void centp_att2_k(const float* __restrict__ partialP,
                                                    const int* __restrict__ idxg,
                                                    const float* __restrict__ kg_w,
                                                    const float* __restrict__ kg_b,
                                                    float* __restrict__ attb) {
    __shared__ float cpm[9][64];
    __shared__ float logit[9];
    __shared__ int   redint[9];
    __shared__ float cnt_sh;
    int b = blockIdx.y, s = blockIdx.x, t = threadIdx.x;
    int k = t >> 6, c = t & 63;

    float sum = 0.f;
    for (int kb = 0; kb < KBLK; ++kb)
        sum += partialP[((size_t)(b * KBLK + kb) * 288 + s * 9 + k) * 64 + c];

    int cloc = 0;
    for (int i = t; i < Np; i += 576) cloc += (idxg[b * Np + i] == s);
    #pragma unroll
    for (int off = 32; off >= 1; off >>= 1) cloc += __shfl_down(cloc, off);
    if ((t & 63) == 0) redint[k] = cloc;
    __syncthreads();
    if (t == 0) {
        int c2 = 0;
        #pragma unroll
        for (int j = 0; j < 9; ++j) c2 += redint[j];
        cnt_sh = fmaxf((float)c2, 1.f);
    }
    __syncthreads();
    cpm[k][c] = sum / cnt_sh;
    __syncthreads();

    float pr = 0.f;
    #pragma unroll
    for (int u = 0; u < 9; ++u)
        pr = fmaf(cpm[u][c], kg_w[k * Dd + c * 9 + u], pr);
    #pragma unroll
    for (int off = 32; off >= 1; off >>= 1) pr += __shfl_down(pr, off);
    if ((t & 63) == 0) logit[k] = pr + kg_b[k];
    __syncthreads();
    if (t == 0) {
        float mx = logit[0];
        #pragma unroll
        for (int jj = 1; jj < 9; ++jj) mx = fmaxf(mx, logit[jj]);
        float e[9], sm = 0.f;
        #pragma unroll
        for (int jj = 0; jj < 9; ++jj) { e[jj] = expf(logit[jj] - mx); sm += e[jj]; }
        #pragma unroll
        for (int jj = 0; jj < 9; ++jj) attb[(b * Sc + s) * 9 + jj] = e[jj] / sm * 9.f;
    }
}

// ---------------- final: 128px x 64out tile; LDS w2 (2 phases); scale-after-MFMA ----------------
__global__ __launch_bounds__(512, 4) void final_out5_k(const float* __restrict__ x,
                                                       const __bf16* __restrict__ fh,
                                                       const int* __restrict__ idxg,
                                                       const float* __restrict__ attb,
                                                       const __bf16* __restrict__ w2kg,
                                                       const float* __restrict__ b2,
                                                       float* __restrict__ out) {
    __shared__ __align__(16) char smem[46080];   // w2l[5][64][72] bf16  /  trans[64][132] f32
    __shared__ float apix_t[9][132];
    __shared__ float b2s[64];
    __bf16 (*w2l)[64][72] = (__bf16 (*)[64][72])smem;
    float (*trans)[132]   = (float (*)[132])smem;

    int b = blockIdx.y, hh = blockIdx.x, n0 = hh * 128, t = threadIdx.x;
    int w = t >> 6, l = t & 63, arow = l & 15, kg = l >> 4;

    if (t < 128) {
        int s = idxg[b * Np + n0 + t];
        const float* ap = attb + (b * Sc + s) * 9;
        #pragma unroll
        for (int k = 0; k < 9; ++k) apix_t[k][t] = ap[k];
    } else if (t < 192) {
        b2s[t - 128] = b2[t - 128];
    }
    // stage w2 k=0..4
    for (int q = t; q < 2560; q += 512) {
        int kk = q >> 9, rem = q & 511, o = rem >> 3, c0 = (rem & 7) * 8;
        *(bf16x8*)&w2l[kk][o][c0] = *(const bf16x8*)&w2kg[(size_t)kk * 4096 + o * 64 + c0];
    }
    __syncthreads();

    int px = w * 16 + arow;        // A-frag row pixel
    f32x4 acc[4];
    #pragma unroll
    for (int nt = 0; nt < 4; ++nt) acc[nt] = (f32x4){0.f, 0.f, 0.f, 0.f};

    #define K_BODY(k, kk)                                                                  \
    {                                                                                      \
        const int dh = (k) / 3 - 1, dw = (k) % 3 - 1;                                      \
        int h2 = hh + dh, wc = px + dw;                                                    \
        bool valid = ((unsigned)h2 < 128u) && ((unsigned)wc < 128u);                       \
        const __bf16* fr = fh + (((size_t)b * Np + (h2 << 7) + wc) << 6);                  \
        bf16x8 av0 = (bf16x8)(__bf16)0.0f, av1 = (bf16x8)(__bf16)0.0f;                     \
        if (valid) {                                                                       \
            av0 = *(const bf16x8*)&fr[kg * 8];                                             \
            av1 = *(const bf16x8*)&fr[32 + kg * 8];                                        \
        }                                                                                  \
        f32x4 a4 = *(const f32x4*)&apix_t[k][w * 16 + kg * 4];                             \
        f32x4 acck[4];                                                                     \
        _Pragma("unroll")                                                                  \
        for (int nt = 0; nt < 4; ++nt) {                                                   \
            bf16x8 bv0 = *(const bf16x8*)&w2l[kk][nt * 16 + arow][kg * 8];                 \
            bf16x8 bv1 = *(const bf16x8*)&w2l[kk][nt * 16 + arow][32 + kg * 8];            \
            acck[nt] = __builtin_amdgcn_mfma_f32_16x16x32_bf16(av0, bv0,                   \
                           (f32x4){0.f, 0.f, 0.f, 0.f}, 0, 0, 0);                          \
            acck[nt] = __builtin_amdgcn_mfma_f32_16x16x32_bf16(av1, bv1, acck[nt], 0, 0, 0);\
        }                                                                                  \
        _Pragma("unroll")                                                                  \
        for (int nt = 0; nt < 4; ++nt)                                                     \
            _Pragma("unroll")                                                              \
            for (int r = 0; r < 4; ++r)                                                    \
                acc[nt][r] = fmaf(a4[r], acck[nt][r], acc[nt][r]);                         \
    }

    K_BODY(0, 0) K_BODY(1, 1) K_BODY(2, 2) K_BODY(3, 3) K_BODY(4, 4)
    __syncthreads();
    // stage w2 k=5..8
    for (int q = t; q < 2048; q += 512) {
        int kk = q >> 9, rem = q & 511, o = rem >> 3, c0 = (rem & 7) * 8;
        *(bf16x8*)&w2l[kk][o][c0] = *(const bf16x8*)&w2kg[(size_t)(kk + 5) * 4096 + o * 64 + c0];
    }
    __syncthreads();
    K_BODY(5, 0) K_BODY(6, 1) K_BODY(7, 2) K_BODY(8, 3)
    #undef K_BODY

    __syncthreads();   // all LDS reads done before trans overwrite
    #pragma unroll
    for (int nt = 0; nt < 4; ++nt)
        #pragma unroll
        for (int r = 0; r < 4; ++r)
            trans[nt * 16 + arow][w * 16 + kg * 4 + r] = acc[nt][r];
    __syncthreads();
    for (int i = t; i < 8192; i += 512) {
        int o = i >> 7, p2 = i & 127;
        size_t gi = ((size_t)b * On + o) * Np + n0 + p2;
        out[gi] = x[gi] + trans[o][p2] + b2s[o];
    }
}

extern "C" void kernel_launch(void* const* d_in, const int* in_sizes, int n_in,
                              void* d_out, int out_size, void* d_ws, size_t ws_size,
                              hipStream_t stream) {
    (void)in_sizes; (void)n_in; (void)out_size; (void)ws_size;
    const float* x    = (const float*)d_in[0];
    const float* kg_w = (const float*)d_in[5];
    const float* kg_b = (const float*)d_in[6];
    const float* w2   = (const float*)d_in[7];
    const float* b2   = (const float*)d_in[8];
    float* out = (float*)d_out;

    char* p = (char*)d_ws;
    __bf16* fh      = (__bf16*)p; p += (size_t)Bn * Np * Cn * 2;     // 16.78 MB
    __bf16* fm      = (__bf16*)p; p += (size_t)Bn * Np * Cn * 2;     // 16.78 MB
    float*  cent_f32= (float*)p;  p += (size_t)Bn * Sc * Cn * 4;
    __bf16* ch_     = (__bf16*)p; p += (size_t)Bn * Sc * Cn * 2;
    __bf16* cm_     = (__bf16*)p; p += (size_t)Bn * Sc * Cn * 2;
    float*  cnorm   = (float*)p;  p += (size_t)Bn * Sc * 4;
    int*    idxg    = (int*)p;    p += (size_t)Bn * Np * 4;
    float*  gpart   = (float*)p;  p += (size_t)Bn * KMB * Sc * 65 * 4;      // 4.26 MB
    float*  partialP= (float*)p;  p += (size_t)Bn * KBLK * 288 * 64 * 4;    // 18.87 MB
    float*  attb    = (float*)p;  p += (size_t)Bn * Sc * 9 * 4;
    __bf16* w2kg    = (__bf16*)p; p += (size_t)9 * On * Cn * 2;

    featbf2_k<<<dim3(Np / 64, Bn), 256, 0, stream>>>(x, fh, fm);
    init_cent3_k<<<dim3(Sc, Bn), 64, 0, stream>>>(x, cent_f32, ch_, cm_, cnorm);
    w2prep_k<<<(On * Dd) / 256, 256, 0, stream>>>(w2, w2kg);

    for (int it = 0; it < KM_ITERS; ++it) {
        kmeans_fused3_k<<<dim3(KMB, Bn), 256, 0, stream>>>(
            x, fh, fm, cent_f32, ch_, cm_, cnorm, idxg, gpart, nullptr, 1);
        update_reduce3_k<<<dim3(Sc, Bn), 256, 0, stream>>>(gpart, cent_f32, ch_, cm_, cnorm);
    }
    // final assignment (writes idx int + float output chunk)
    kmeans_fused3_k<<<dim3(KMB, Bn), 256, 0, stream>>>(
        x, fh, fm, cent_f32, ch_, cm_, cnorm, idxg, gpart,
        out + (size_t)Bn * On * Np, 0);

    centp_mfma_k<<<dim3(KBLK, Bn), 512, 0, stream>>>(x, idxg, partialP);
    centp_att2_k<<<dim3(Sc, Bn), 576, 0, stream>>>(partialP, idxg, kg_w, kg_b, attb);

    final_out5_k<<<dim3(128, Bn), 512, 0, stream>>>(x, fh, idxg, attb, w2kg, b2, out);
}